// Round 1
// 195.567 us; speedup vs baseline: 1.0105x; 1.0105x over previous
//
#include <hip/hip_runtime.h>
#include <math.h>

#define V 32768
#define D 15
#define DM 1024
#define B 8
#define T 1024
#define NNODES (V - 1)  // 32767
#define NK1 8191        // heap idx 0..8190 = levels 2..14 (leaf-to-root): computed densely by k1.
                        // Levels 0..1 (heap idx 8191..32766, 75% of W) are computed per-target
                        // in k2 via gather — their per-target reuse is only ~1.3-1.6x, so dense
                        // precompute wastes ~50 MB of DRAM traffic vs gathering distinct rows.
#define R 4             // rows per pass per wave; 2 passes -> 8 rows/wave, 32/block

// Native vector type: __builtin_nontemporal_load requires a pointer to a scalar
// or native vector type; HIP's float4 (HIP_vector_type struct) is rejected.
typedef float vfloat4 __attribute__((ext_vector_type(4)));

// Kernel 1: sig[v*B + b] = sigmoid(dot(W[v], x[b]) + bias[v]) for heap idx v < NK1 only.
// Grid 256 x 256 threads (4 waves). Each wave: 2 passes of R=4 rows, K split across
// 64 lanes (4 float4 per lane per row), one-iteration W prefetch.
//
// R6 theory: dur is DRAM-floor bound — the 512 MB ws-poison drains ~256 MB of dirty
// MALL lines during k1's window (WRITE_SIZE counts TCC->fabric, not DRAM). The only
// lever is total DRAM bytes: k1 now reads 33.5 MB (rows 0..8190) instead of 134 MB;
// the leaf-side 100.7 MB moves to k2 as ~48 MB of distinct gathered rows.
// R3 lesson preserved: all acc[] indices are compile-time constants (no scratch).
__global__ __launch_bounds__(256, 4) void hsm_logits_kernel(
    const float* __restrict__ x,     // [B][DM]
    const float* __restrict__ W,     // [NNODES][DM]
    const float* __restrict__ bias,  // [NNODES]
    float* __restrict__ sig)         // [NK1][B]
{
    __shared__ vfloat4 xs[B * DM / 4];  // 32 KB, xs[b*256 + u]

    const vfloat4* x4 = (const vfloat4*)x;
    #pragma unroll
    for (int i = threadIdx.x; i < B * DM / 4; i += 256) xs[i] = x4[i];
    __syncthreads();

    const int wave = __builtin_amdgcn_readfirstlane(threadIdx.x >> 6);  // scalarize
    const int lane = threadIdx.x & 63;
    const int rowbase = blockIdx.x * 32 + wave * 8;

    const vfloat4* Wb = (const vfloat4*)W;

    vfloat4 wv[R], wvn[R];
    float acc[R * B];  // acc[r*8+b]

    // Preload pass-0, j=0 (nontemporal: these W lines are single-use per iteration).
    #pragma unroll
    for (int r = 0; r < R; r++) {
        int row = rowbase + r;
        if (row > NK1 - 1) row = NK1 - 1;  // scalar clamp; store guarded below
        wv[r] = __builtin_nontemporal_load(&Wb[(size_t)row * 256 + lane]);
    }

    auto run_pass = [&](int prow0, bool preload_next, int nrow0) {
        #pragma unroll
        for (int i = 0; i < R * B; i++) acc[i] = 0.f;
        #pragma unroll
        for (int j = 0; j < 4; j++) {
            if (j < 3) {
                #pragma unroll
                for (int r = 0; r < R; r++) {
                    int row = prow0 + r;
                    if (row > NK1 - 1) row = NK1 - 1;
                    wvn[r] = __builtin_nontemporal_load(
                        &Wb[(size_t)row * 256 + (j + 1) * 64 + lane]);
                }
            } else if (preload_next) {
                #pragma unroll
                for (int r = 0; r < R; r++) {
                    int row = nrow0 + r;
                    if (row > NK1 - 1) row = NK1 - 1;
                    wvn[r] = __builtin_nontemporal_load(
                        &Wb[(size_t)row * 256 + lane]);
                }
            }
            vfloat4 xv[B];
            #pragma unroll
            for (int b = 0; b < B; b++) xv[b] = xs[b * 256 + j * 64 + lane];
            #pragma unroll
            for (int r = 0; r < R; r++) {
                #pragma unroll
                for (int b = 0; b < B; b++) {
                    acc[r * 8 + b] += wv[r].x * xv[b].x + wv[r].y * xv[b].y +
                                      wv[r].z * xv[b].z + wv[r].w * xv[b].w;
                }
            }
            #pragma unroll
            for (int r = 0; r < R; r++) wv[r] = wvn[r];
        }
    };

#define FOLD_LEVEL(MASK, NOUT)                                   \
    _Pragma("unroll")                                            \
    for (int i = 0; i < (NOUT); i++) {                           \
        const float lo = acc[2 * i];                             \
        const float hi = acc[2 * i + 1];                         \
        const float send = (lane & (MASK)) ? lo : hi;            \
        const float keep = (lane & (MASK)) ? hi : lo;            \
        acc[i] = keep + __shfl_xor(send, (MASK), 64);            \
    }

    auto fold_store = [&](int prow0) {
        FOLD_LEVEL(1, 16)
        FOLD_LEVEL(2, 8)
        FOLD_LEVEL(4, 4)
        FOLD_LEVEL(8, 2)
        FOLD_LEVEL(16, 1)
        acc[0] += __shfl_xor(acc[0], 32, 64);  // combine halves
        if (lane < 32) {
            const int r = lane >> 3;
            const int b = lane & 7;
            const int row = prow0 + r;
            if (row < NK1) {
                const float z = acc[0] + bias[row];
                sig[(size_t)row * B + b] = 1.f / (1.f + expf(-z));  // cached: k2 reads it
            }
        }
    };

    run_pass(rowbase, true, rowbase + R);
    fold_store(rowbase);           // epilogue overlaps pass-1's in-flight loads
    run_pass(rowbase + R, false, 0);
    fold_store(rowbase + R);
#undef FOLD_LEVEL
}

// Kernel 2: one wave per target (b,t). The two leaf-side levels are computed here as
// gathered dot-products (W rows r0, r1 derived arithmetically from id); levels 2..14
// come from the sig table. Heap-index arithmetic: with m = id + V, the l-th internal
// node on the leaf-to-root path is (m >> (l+1)) - 1 (verified against _build_paths).
// W gather rows are read with PLAIN loads (1.3-1.6x per-target reuse -> let MALL/L2
// absorb the repeats); x (32 KB) is L1/L2-hot, no LDS staging needed.
__global__ __launch_bounds__(256) void hsm_prod_kernel(
    const float* __restrict__ x,     // [B][DM]
    const int* __restrict__ ids,     // [B][T]
    const float* __restrict__ W,     // [NNODES][DM]
    const float* __restrict__ bias,  // [NNODES]
    const float* __restrict__ sig,   // [NK1][B]
    float* __restrict__ out)         // [B][T]
{
    const int wave = threadIdx.x >> 6;
    const int lane = threadIdx.x & 63;
    const int i = blockIdx.x * 4 + wave;  // target index in [0, B*T)
    if (i >= B * T) return;               // wave-uniform guard (grid is exact anyway)
    const int b = i >> 10;                // T = 1024
    const int id = ids[i];                // same addr across lanes -> one request
    const unsigned m = (unsigned)id + V;
    const int r0 = (int)(m >> 1) - 1;     // level 0 node (leaf parent), in [16383, 32766]
    const int r1 = (int)(m >> 2) - 1;     // level 1 node, in [8191, 16382]

    const vfloat4* W4 = (const vfloat4*)W;
    const vfloat4* x4 = (const vfloat4*)x;

    // Issue all global loads up front so HBM latency overlaps.
    vfloat4 w0[4], w1[4], xv[4];
    #pragma unroll
    for (int j = 0; j < 4; j++) w0[j] = W4[(size_t)r0 * 256 + j * 64 + lane];
    #pragma unroll
    for (int j = 0; j < 4; j++) w1[j] = W4[(size_t)r1 * 256 + j * 64 + lane];
    #pragma unroll
    for (int j = 0; j < 4; j++) xv[j] = x4[b * 256 + j * 64 + lane];
    const float bb0 = bias[r0];  // wave-uniform broadcast loads
    const float bb1 = bias[r1];

    float a0 = 0.f, a1 = 0.f;
    #pragma unroll
    for (int j = 0; j < 4; j++) {
        a0 += w0[j].x * xv[j].x + w0[j].y * xv[j].y + w0[j].z * xv[j].z + w0[j].w * xv[j].w;
        a1 += w1[j].x * xv[j].x + w1[j].y * xv[j].y + w1[j].z * xv[j].z + w1[j].w * xv[j].w;
    }
    // Full-wave butterfly sum-reduce (both dots; all lanes end with the totals).
    #pragma unroll
    for (int s = 1; s < 64; s <<= 1) {
        a0 += __shfl_xor(a0, s, 64);
        a1 += __shfl_xor(a1, s, 64);
    }

    // Levels 2..14: 13 sig gathers spread over lanes 0..12, then multiply-reduce
    // within the 16-lane group (lanes 13..15 contribute 1.0).
    float p = 1.f;
    if (lane < 13) {
        const int nl = (int)(m >> (lane + 3)) - 1;  // level l = lane+2 -> shift l+1
        p = sig[(size_t)nl * B + b];
    }
    #pragma unroll
    for (int s = 1; s < 16; s <<= 1) p *= __shfl_xor(p, s, 64);

    if (lane == 0) {
        const float s0 = 1.f / (1.f + expf(-(a0 + bb0)));
        const float s1 = 1.f / (1.f + expf(-(a1 + bb1)));
        out[i] = p * s0 * s1;
    }
}

extern "C" void kernel_launch(void* const* d_in, const int* in_sizes, int n_in,
                              void* d_out, int out_size, void* d_ws, size_t ws_size,
                              hipStream_t stream) {
    const float* x     = (const float*)d_in[0];  // [B, DM]
    const int*   ids   = (const int*)d_in[1];    // [B, T]
    const float* W     = (const float*)d_in[3];  // [NNODES, DM]
    const float* bias  = (const float*)d_in[4];  // [NNODES]
    float* out = (float*)d_out;                  // [B, T]
    float* sig = (float*)d_ws;                   // [NK1, B] = 256 KB scratch

    const int grid1 = (NK1 + 31) / 32;  // 256 blocks x 32 rows = 8192 >= NK1
    hsm_logits_kernel<<<grid1, 256, 0, stream>>>(x, W, bias, sig);

    const int grid2 = (B * T) / 4;  // 2048 blocks, one wave (of 4) per target
    hsm_prod_kernel<<<grid2, 256, 0, stream>>>(x, ids, W, bias, sig, out);
}